// Round 8
// baseline (501.203 us; speedup 1.0000x reference)
//
#include <hip/hip_runtime.h>
#include <math.h>

#define BNUM 16
#define HNUM 512
#define WNUM 512
#define HW (HNUM*WNUM)            // 262144
#define NPLANE (BNUM*HW)          // 4194304
#define RR 8
#define KWIN 17
#define EPSF 1e-5f
#define THRESHF 0.8f
#define STRIP 128
#define SEG 16
#define RPG 4                      // rows per group (batched per barrier)
#define NGRP ((SEG + 2*RR) / RPG)  // 8 groups: 0-3 ramp, 4-7 emit
#define INV_KK (1.0f/289.0f)
#define INV_NUMEL (1.0f/12582912.0f)

// ---------------- Kernel 1: per-pixel prep ----------------
__global__ __launch_bounds__(256) void prep_kernel(
        const float* __restrict__ outp, const float* __restrict__ inp,
        float* __restrict__ PI, float* __restrict__ PP, float* __restrict__ PS) {
    int pix = (blockIdx.x * 256 + threadIdx.x) * 4;
    if (pix >= NPLANE) return;
    int b = pix >> 18;
    int r = pix & (HW - 1);
    size_t base = (size_t)b * 3 * HW + r;

    float4 a0 = *(const float4*)(inp + base);
    float4 a1 = *(const float4*)(inp + base + HW);
    float4 a2 = *(const float4*)(inp + base + 2 * HW);
    float4 b0 = *(const float4*)(outp + base);
    float4 b1 = *(const float4*)(outp + base + HW);
    float4 b2 = *(const float4*)(outp + base + 2 * HW);

    float4 I4, P4, S4;
#define DOCOMP(M) { \
    float i0 = (a0.M + 1.f) * 0.5f; \
    float i1 = (a1.M + 1.f) * 0.5f; \
    float i2 = (a2.M + 1.f) * 0.5f; \
    I4.M = (i0 + i1 + i2) * (1.f/3.f); \
    float mx = fmaxf(i0, fmaxf(i1, i2)); \
    P4.M = (mx > THRESHF) ? 1.f : 0.f; \
    S4.M = 0.5f * (fabsf(b0.M - a0.M) + fabsf(b1.M - a1.M) + fabsf(b2.M - a2.M)); \
}
    DOCOMP(x) DOCOMP(y) DOCOMP(z) DOCOMP(w)
#undef DOCOMP

    size_t po = (size_t)b * HW + r;
    *(float4*)(PI + po) = I4;
    *(float4*)(PP + po) = P4;
    *(float4*)(PS + po) = S4;
}

// ---------------- Kernel 2: box(I,p,I*p,I*I) -> a,b ----------------
// 4 rows per barrier; vertical 17-ring held in REGISTERS (static indices only:
// shift-by-4 fully unrolled). LDS = 2(dbuf) x 4(rows) x 144 x 2 arrays = 9.2KB.
__global__ __launch_bounds__(STRIP, 4) void boxc_ab(
        const float* __restrict__ PI, const float* __restrict__ PP,
        float* __restrict__ PA, float* __restrict__ PB) {
    __shared__ float rowI[2][RPG][STRIP + 2 * RR];
    __shared__ float rowP[2][RPG][STRIP + 2 * RR];

    int t  = threadIdx.x;
    int x0 = blockIdx.x * STRIP;
    int ys = blockIdx.y * SEG;
    int b  = blockIdx.z;

    const float* Ib = PI + (size_t)b * HW;
    const float* Pb = PP + (size_t)b * HW;
    float* Ab = PA + (size_t)b * HW;
    float* Bb = PB + (size_t)b * HW;

    int xg  = x0 - RR + t;
    bool xok  = (xg >= 0) && (xg < WNUM);
    int xg2 = x0 - RR + STRIP + t;
    bool x2ok = (t < 2 * RR) && (xg2 < WNUM);

    float ringI[KWIN], ringP[KWIN], ringIp[KWIN], ringII[KWIN];
#pragma unroll
    for (int i = 0; i < KWIN; ++i) { ringI[i]=0.f; ringP[i]=0.f; ringIp[i]=0.f; ringII[i]=0.f; }
    float vI = 0.f, vP = 0.f, vIp = 0.f, vII = 0.f;

    // prefetch group 0 (4 rows x {I,P} x {main,tail})
    float pi0[RPG], pp0[RPG], pi1[RPG], pp1[RPG];
#pragma unroll
    for (int r = 0; r < RPG; ++r) {
        pi0[r]=0.f; pp0[r]=0.f; pi1[r]=0.f; pp1[r]=0.f;
        int y = ys - RR + r;
        if (y >= 0 && y < HNUM) {
            size_t ro = (size_t)y * WNUM;
            if (xok)  { pi0[r] = Ib[ro + xg];  pp0[r] = Pb[ro + xg]; }
            if (x2ok) { pi1[r] = Ib[ro + xg2]; pp1[r] = Pb[ro + xg2]; }
        }
    }

    int cur = 0;
    for (int g = 0; g < NGRP; ++g) {
        int ybase = ys - RR + g * RPG;
        // publish current group's rows
#pragma unroll
        for (int r = 0; r < RPG; ++r) { rowI[cur][r][t] = pi0[r]; rowP[cur][r][t] = pp0[r]; }
        if (t < 2 * RR) {
#pragma unroll
            for (int r = 0; r < RPG; ++r) { rowI[cur][r][STRIP+t] = pi1[r]; rowP[cur][r][STRIP+t] = pp1[r]; }
        }
        // issue next group's loads (4 independent rows in flight)
#pragma unroll
        for (int r = 0; r < RPG; ++r) { pi0[r]=0.f; pp0[r]=0.f; pi1[r]=0.f; pp1[r]=0.f; }
        if (g + 1 < NGRP) {
#pragma unroll
            for (int r = 0; r < RPG; ++r) {
                int y = ybase + RPG + r;
                if (y >= 0 && y < HNUM) {
                    size_t ro = (size_t)y * WNUM;
                    if (xok)  { pi0[r] = Ib[ro + xg];  pp0[r] = Pb[ro + xg]; }
                    if (x2ok) { pi1[r] = Ib[ro + xg2]; pp1[r] = Pb[ro + xg2]; }
                }
            }
        }
        __syncthreads();

        // 4 rows of 17-tap horizontal sums
        float sI[RPG], sP[RPG], sIp[RPG], sII[RPG];
#pragma unroll
        for (int r = 0; r < RPG; ++r) {
            float aI=0.f, aP=0.f, aIp=0.f, aII=0.f;
#pragma unroll
            for (int d = 0; d < KWIN; ++d) {
                float iv = rowI[cur][r][t + d];
                float pv = rowP[cur][r][t + d];
                aI += iv; aP += pv; aIp += iv * pv; aII += iv * iv;
            }
            sI[r]=aI; sP[r]=aP; sIp[r]=aIp; sII[r]=aII;
        }

        bool emit = (g >= (2 * RR) / RPG);   // uniform per-g
#pragma unroll
        for (int r = 0; r < RPG; ++r) {
            vI  += sI[r]  - ringI[r];
            vP  += sP[r]  - ringP[r];
            vIp += sIp[r] - ringIp[r];
            vII += sII[r] - ringII[r];
            if (emit) {
                int yout = ybase + r - RR;
                float mI  = vI  * INV_KK;
                float mP  = vP  * INV_KK;
                float mIp = vIp * INV_KK;
                float mII = vII * INV_KK;
                float cov = mIp - mI * mP;
                float var = mII - mI * mI;
                float a   = cov / (var + EPSF);
                float bb  = mP - a * mI;
                size_t off = (size_t)yout * WNUM + x0 + t;
                Ab[off] = a;
                Bb[off] = bb;
            }
        }
        // shift ring by RPG (all-static indices)
#pragma unroll
        for (int i = 0; i < KWIN - RPG; ++i) {
            ringI[i]=ringI[i+RPG]; ringP[i]=ringP[i+RPG];
            ringIp[i]=ringIp[i+RPG]; ringII[i]=ringII[i+RPG];
        }
#pragma unroll
        for (int r = 0; r < RPG; ++r) {
            ringI[KWIN-RPG+r]=sI[r]; ringP[KWIN-RPG+r]=sP[r];
            ringIp[KWIN-RPG+r]=sIp[r]; ringII[KWIN-RPG+r]=sII[r];
        }
        cur ^= 1;
    }
}

// ---------------- Kernel 3: box(a), box(b) -> mask -> loss ----------------
__global__ __launch_bounds__(STRIP, 4) void boxc_mask_loss(
        const float* __restrict__ PA, const float* __restrict__ PB,
        const float* __restrict__ PI, const float* __restrict__ PS,
        float* __restrict__ loss_out) {
    __shared__ float rowA[2][RPG][STRIP + 2 * RR];
    __shared__ float rowB[2][RPG][STRIP + 2 * RR];
    __shared__ float red[2];

    int t  = threadIdx.x;
    int x0 = blockIdx.x * STRIP;
    int ys = blockIdx.y * SEG;
    int b  = blockIdx.z;

    const float* Ab = PA + (size_t)b * HW;
    const float* Bb = PB + (size_t)b * HW;
    const float* Ib = PI + (size_t)b * HW;
    const float* Sb = PS + (size_t)b * HW;

    int xg  = x0 - RR + t;
    bool xok  = (xg >= 0) && (xg < WNUM);
    int xg2 = x0 - RR + STRIP + t;
    bool x2ok = (t < 2 * RR) && (xg2 < WNUM);

    float ringA[KWIN], ringB[KWIN];
#pragma unroll
    for (int i = 0; i < KWIN; ++i) { ringA[i]=0.f; ringB[i]=0.f; }
    float vA = 0.f, vB = 0.f;
    float partial = 0.f;

    float pa0[RPG], pb0[RPG], pa1[RPG], pb1[RPG];
#pragma unroll
    for (int r = 0; r < RPG; ++r) {
        pa0[r]=0.f; pb0[r]=0.f; pa1[r]=0.f; pb1[r]=0.f;
        int y = ys - RR + r;
        if (y >= 0 && y < HNUM) {
            size_t ro = (size_t)y * WNUM;
            if (xok)  { pa0[r] = Ab[ro + xg];  pb0[r] = Bb[ro + xg]; }
            if (x2ok) { pa1[r] = Ab[ro + xg2]; pb1[r] = Bb[ro + xg2]; }
        }
    }

    int cur = 0;
    for (int g = 0; g < NGRP; ++g) {
        int ybase = ys - RR + g * RPG;
#pragma unroll
        for (int r = 0; r < RPG; ++r) { rowA[cur][r][t] = pa0[r]; rowB[cur][r][t] = pb0[r]; }
        if (t < 2 * RR) {
#pragma unroll
            for (int r = 0; r < RPG; ++r) { rowA[cur][r][STRIP+t] = pa1[r]; rowB[cur][r][STRIP+t] = pb1[r]; }
        }
#pragma unroll
        for (int r = 0; r < RPG; ++r) { pa0[r]=0.f; pb0[r]=0.f; pa1[r]=0.f; pb1[r]=0.f; }
        if (g + 1 < NGRP) {
#pragma unroll
            for (int r = 0; r < RPG; ++r) {
                int y = ybase + RPG + r;
                if (y >= 0 && y < HNUM) {
                    size_t ro = (size_t)y * WNUM;
                    if (xok)  { pa0[r] = Ab[ro + xg];  pb0[r] = Bb[ro + xg]; }
                    if (x2ok) { pa1[r] = Ab[ro + xg2]; pb1[r] = Bb[ro + xg2]; }
                }
            }
        }
        __syncthreads();

        float sA[RPG], sB[RPG];
#pragma unroll
        for (int r = 0; r < RPG; ++r) {
            float aA=0.f, aB=0.f;
#pragma unroll
            for (int d = 0; d < KWIN; ++d) {
                aA += rowA[cur][r][t + d];
                aB += rowB[cur][r][t + d];
            }
            sA[r]=aA; sB[r]=aB;
        }

        bool emit = (g >= (2 * RR) / RPG);
#pragma unroll
        for (int r = 0; r < RPG; ++r) {
            vA += sA[r] - ringA[r];
            vB += sB[r] - ringB[r];
            if (emit) {
                int yout = ybase + r - RR;
                float mA = vA * INV_KK;
                float mB = vB * INV_KK;
                size_t off = (size_t)yout * WNUM + x0 + t;
                float refined = mA * Ib[off] + mB;
                float mask = fminf(fmaxf(refined, 0.f), 1.f);
                partial += mask * Sb[off];
            }
        }
#pragma unroll
        for (int i = 0; i < KWIN - RPG; ++i) { ringA[i]=ringA[i+RPG]; ringB[i]=ringB[i+RPG]; }
#pragma unroll
        for (int r = 0; r < RPG; ++r) { ringA[KWIN-RPG+r]=sA[r]; ringB[KWIN-RPG+r]=sB[r]; }
        cur ^= 1;
    }

    // block reduction: 2 waves of 64
#pragma unroll
    for (int off = 32; off > 0; off >>= 1)
        partial += __shfl_down(partial, off);
    if ((t & 63) == 0) red[t >> 6] = partial;
    __syncthreads();
    if (t == 0) atomicAdd(loss_out, (red[0] + red[1]) * INV_NUMEL);
}

extern "C" void kernel_launch(void* const* d_in, const int* in_sizes, int n_in,
                              void* d_out, int out_size, void* d_ws, size_t ws_size,
                              hipStream_t stream) {
    const float* outp = (const float*)d_in[0];
    const float* inp  = (const float*)d_in[1];

    float* ws = (float*)d_ws;
    float* PI = ws;
    float* PP = ws + (size_t)NPLANE;
    float* PS = ws + (size_t)2 * NPLANE;
    float* PA = ws + (size_t)3 * NPLANE;
    float* PB = ws + (size_t)4 * NPLANE;

    hipMemsetAsync(d_out, 0, sizeof(float), stream);

    prep_kernel<<<NPLANE / (256 * 4), 256, 0, stream>>>(outp, inp, PI, PP, PS);

    dim3 grid(WNUM / STRIP, HNUM / SEG, BNUM);   // 4 x 32 x 16 = 2048 blocks
    boxc_ab<<<grid, STRIP, 0, stream>>>(PI, PP, PA, PB);
    boxc_mask_loss<<<grid, STRIP, 0, stream>>>(PA, PB, PI, PS, (float*)d_out);
}

// Round 9
// 226.581 us; speedup vs baseline: 2.2120x; 2.2120x over previous
//
#include <hip/hip_runtime.h>
#include <math.h>

#define BNUM 16
#define HNUM 512
#define WNUM 512
#define HW (HNUM*WNUM)            // 262144
#define NPLANE (BNUM*HW)          // 4194304
#define RR 8
#define KWIN 17
#define EPSF 1e-5f
#define THRESHF 0.8f
#define STRIP 128
#define SEG 16
#define RPG 4                      // rows per group (batched per barrier)
#define NGRP ((SEG + 2*RR) / RPG)  // 8 groups: 0-3 ramp, 4-7 emit
#define INV_KK (1.0f/289.0f)
#define INV_NUMEL (1.0f/12582912.0f)

// ---------------- Kernel 1: per-pixel prep ----------------
__global__ __launch_bounds__(256) void prep_kernel(
        const float* __restrict__ outp, const float* __restrict__ inp,
        float* __restrict__ PI, float* __restrict__ PP, float* __restrict__ PS) {
    int pix = (blockIdx.x * 256 + threadIdx.x) * 4;
    if (pix >= NPLANE) return;
    int b = pix >> 18;
    int r = pix & (HW - 1);
    size_t base = (size_t)b * 3 * HW + r;

    float4 a0 = *(const float4*)(inp + base);
    float4 a1 = *(const float4*)(inp + base + HW);
    float4 a2 = *(const float4*)(inp + base + 2 * HW);
    float4 b0 = *(const float4*)(outp + base);
    float4 b1 = *(const float4*)(outp + base + HW);
    float4 b2 = *(const float4*)(outp + base + 2 * HW);

    float4 I4, P4, S4;
#define DOCOMP(M) { \
    float i0 = (a0.M + 1.f) * 0.5f; \
    float i1 = (a1.M + 1.f) * 0.5f; \
    float i2 = (a2.M + 1.f) * 0.5f; \
    I4.M = (i0 + i1 + i2) * (1.f/3.f); \
    float mx = fmaxf(i0, fmaxf(i1, i2)); \
    P4.M = (mx > THRESHF) ? 1.f : 0.f; \
    S4.M = 0.5f * (fabsf(b0.M - a0.M) + fabsf(b1.M - a1.M) + fabsf(b2.M - a2.M)); \
}
    DOCOMP(x) DOCOMP(y) DOCOMP(z) DOCOMP(w)
#undef DOCOMP

    size_t po = (size_t)b * HW + r;
    *(float4*)(PI + po) = I4;
    *(float4*)(PP + po) = P4;
    *(float4*)(PS + po) = S4;
}

// ---------------- Kernel 2: box(I,p,I*p,I*I) -> a,b ----------------
// 4 rows per barrier; vertical 17-ring held in REGISTERS (static indices only:
// shift-by-4 fully unrolled). LDS = 9.2KB. NO min-waves clamp: the rings need
// ~120 VGPR; capping at 64 (R8) spilled them to scratch -> 1 GB HBM traffic.
__global__ __launch_bounds__(STRIP) void boxc_ab(
        const float* __restrict__ PI, const float* __restrict__ PP,
        float* __restrict__ PA, float* __restrict__ PB) {
    __shared__ float rowI[2][RPG][STRIP + 2 * RR];
    __shared__ float rowP[2][RPG][STRIP + 2 * RR];

    int t  = threadIdx.x;
    int x0 = blockIdx.x * STRIP;
    int ys = blockIdx.y * SEG;
    int b  = blockIdx.z;

    const float* Ib = PI + (size_t)b * HW;
    const float* Pb = PP + (size_t)b * HW;
    float* Ab = PA + (size_t)b * HW;
    float* Bb = PB + (size_t)b * HW;

    int xg  = x0 - RR + t;
    bool xok  = (xg >= 0) && (xg < WNUM);
    int xg2 = x0 - RR + STRIP + t;
    bool x2ok = (t < 2 * RR) && (xg2 < WNUM);

    float ringI[KWIN], ringP[KWIN], ringIp[KWIN], ringII[KWIN];
#pragma unroll
    for (int i = 0; i < KWIN; ++i) { ringI[i]=0.f; ringP[i]=0.f; ringIp[i]=0.f; ringII[i]=0.f; }
    float vI = 0.f, vP = 0.f, vIp = 0.f, vII = 0.f;

    // prefetch group 0 (4 rows x {I,P} x {main,tail})
    float pi0[RPG], pp0[RPG], pi1[RPG], pp1[RPG];
#pragma unroll
    for (int r = 0; r < RPG; ++r) {
        pi0[r]=0.f; pp0[r]=0.f; pi1[r]=0.f; pp1[r]=0.f;
        int y = ys - RR + r;
        if (y >= 0 && y < HNUM) {
            size_t ro = (size_t)y * WNUM;
            if (xok)  { pi0[r] = Ib[ro + xg];  pp0[r] = Pb[ro + xg]; }
            if (x2ok) { pi1[r] = Ib[ro + xg2]; pp1[r] = Pb[ro + xg2]; }
        }
    }

    int cur = 0;
    for (int g = 0; g < NGRP; ++g) {
        int ybase = ys - RR + g * RPG;
        // publish current group's rows
#pragma unroll
        for (int r = 0; r < RPG; ++r) { rowI[cur][r][t] = pi0[r]; rowP[cur][r][t] = pp0[r]; }
        if (t < 2 * RR) {
#pragma unroll
            for (int r = 0; r < RPG; ++r) { rowI[cur][r][STRIP+t] = pi1[r]; rowP[cur][r][STRIP+t] = pp1[r]; }
        }
        // issue next group's loads (4 independent rows in flight)
#pragma unroll
        for (int r = 0; r < RPG; ++r) { pi0[r]=0.f; pp0[r]=0.f; pi1[r]=0.f; pp1[r]=0.f; }
        if (g + 1 < NGRP) {
#pragma unroll
            for (int r = 0; r < RPG; ++r) {
                int y = ybase + RPG + r;
                if (y >= 0 && y < HNUM) {
                    size_t ro = (size_t)y * WNUM;
                    if (xok)  { pi0[r] = Ib[ro + xg];  pp0[r] = Pb[ro + xg]; }
                    if (x2ok) { pi1[r] = Ib[ro + xg2]; pp1[r] = Pb[ro + xg2]; }
                }
            }
        }
        __syncthreads();

        // 4 rows of 17-tap horizontal sums
        float sI[RPG], sP[RPG], sIp[RPG], sII[RPG];
#pragma unroll
        for (int r = 0; r < RPG; ++r) {
            float aI=0.f, aP=0.f, aIp=0.f, aII=0.f;
#pragma unroll
            for (int d = 0; d < KWIN; ++d) {
                float iv = rowI[cur][r][t + d];
                float pv = rowP[cur][r][t + d];
                aI += iv; aP += pv; aIp += iv * pv; aII += iv * iv;
            }
            sI[r]=aI; sP[r]=aP; sIp[r]=aIp; sII[r]=aII;
        }

        bool emit = (g >= (2 * RR) / RPG);   // uniform per-g
#pragma unroll
        for (int r = 0; r < RPG; ++r) {
            vI  += sI[r]  - ringI[r];
            vP  += sP[r]  - ringP[r];
            vIp += sIp[r] - ringIp[r];
            vII += sII[r] - ringII[r];
            if (emit) {
                int yout = ybase + r - RR;
                float mI  = vI  * INV_KK;
                float mP  = vP  * INV_KK;
                float mIp = vIp * INV_KK;
                float mII = vII * INV_KK;
                float cov = mIp - mI * mP;
                float var = mII - mI * mI;
                float a   = cov / (var + EPSF);
                float bb  = mP - a * mI;
                size_t off = (size_t)yout * WNUM + x0 + t;
                Ab[off] = a;
                Bb[off] = bb;
            }
        }
        // shift ring by RPG (all-static indices)
#pragma unroll
        for (int i = 0; i < KWIN - RPG; ++i) {
            ringI[i]=ringI[i+RPG]; ringP[i]=ringP[i+RPG];
            ringIp[i]=ringIp[i+RPG]; ringII[i]=ringII[i+RPG];
        }
#pragma unroll
        for (int r = 0; r < RPG; ++r) {
            ringI[KWIN-RPG+r]=sI[r]; ringP[KWIN-RPG+r]=sP[r];
            ringIp[KWIN-RPG+r]=sIp[r]; ringII[KWIN-RPG+r]=sII[r];
        }
        cur ^= 1;
    }
}

// ---------------- Kernel 3: box(a), box(b) -> mask -> loss ----------------
__global__ __launch_bounds__(STRIP) void boxc_mask_loss(
        const float* __restrict__ PA, const float* __restrict__ PB,
        const float* __restrict__ PI, const float* __restrict__ PS,
        float* __restrict__ loss_out) {
    __shared__ float rowA[2][RPG][STRIP + 2 * RR];
    __shared__ float rowB[2][RPG][STRIP + 2 * RR];
    __shared__ float red[2];

    int t  = threadIdx.x;
    int x0 = blockIdx.x * STRIP;
    int ys = blockIdx.y * SEG;
    int b  = blockIdx.z;

    const float* Ab = PA + (size_t)b * HW;
    const float* Bb = PB + (size_t)b * HW;
    const float* Ib = PI + (size_t)b * HW;
    const float* Sb = PS + (size_t)b * HW;

    int xg  = x0 - RR + t;
    bool xok  = (xg >= 0) && (xg < WNUM);
    int xg2 = x0 - RR + STRIP + t;
    bool x2ok = (t < 2 * RR) && (xg2 < WNUM);

    float ringA[KWIN], ringB[KWIN];
#pragma unroll
    for (int i = 0; i < KWIN; ++i) { ringA[i]=0.f; ringB[i]=0.f; }
    float vA = 0.f, vB = 0.f;
    float partial = 0.f;

    float pa0[RPG], pb0[RPG], pa1[RPG], pb1[RPG];
#pragma unroll
    for (int r = 0; r < RPG; ++r) {
        pa0[r]=0.f; pb0[r]=0.f; pa1[r]=0.f; pb1[r]=0.f;
        int y = ys - RR + r;
        if (y >= 0 && y < HNUM) {
            size_t ro = (size_t)y * WNUM;
            if (xok)  { pa0[r] = Ab[ro + xg];  pb0[r] = Bb[ro + xg]; }
            if (x2ok) { pa1[r] = Ab[ro + xg2]; pb1[r] = Bb[ro + xg2]; }
        }
    }

    int cur = 0;
    for (int g = 0; g < NGRP; ++g) {
        int ybase = ys - RR + g * RPG;
#pragma unroll
        for (int r = 0; r < RPG; ++r) { rowA[cur][r][t] = pa0[r]; rowB[cur][r][t] = pb0[r]; }
        if (t < 2 * RR) {
#pragma unroll
            for (int r = 0; r < RPG; ++r) { rowA[cur][r][STRIP+t] = pa1[r]; rowB[cur][r][STRIP+t] = pb1[r]; }
        }
#pragma unroll
        for (int r = 0; r < RPG; ++r) { pa0[r]=0.f; pb0[r]=0.f; pa1[r]=0.f; pb1[r]=0.f; }
        if (g + 1 < NGRP) {
#pragma unroll
            for (int r = 0; r < RPG; ++r) {
                int y = ybase + RPG + r;
                if (y >= 0 && y < HNUM) {
                    size_t ro = (size_t)y * WNUM;
                    if (xok)  { pa0[r] = Ab[ro + xg];  pb0[r] = Bb[ro + xg]; }
                    if (x2ok) { pa1[r] = Ab[ro + xg2]; pb1[r] = Bb[ro + xg2]; }
                }
            }
        }
        __syncthreads();

        float sA[RPG], sB[RPG];
#pragma unroll
        for (int r = 0; r < RPG; ++r) {
            float aA=0.f, aB=0.f;
#pragma unroll
            for (int d = 0; d < KWIN; ++d) {
                aA += rowA[cur][r][t + d];
                aB += rowB[cur][r][t + d];
            }
            sA[r]=aA; sB[r]=aB;
        }

        bool emit = (g >= (2 * RR) / RPG);
#pragma unroll
        for (int r = 0; r < RPG; ++r) {
            vA += sA[r] - ringA[r];
            vB += sB[r] - ringB[r];
            if (emit) {
                int yout = ybase + r - RR;
                float mA = vA * INV_KK;
                float mB = vB * INV_KK;
                size_t off = (size_t)yout * WNUM + x0 + t;
                float refined = mA * Ib[off] + mB;
                float mask = fminf(fmaxf(refined, 0.f), 1.f);
                partial += mask * Sb[off];
            }
        }
#pragma unroll
        for (int i = 0; i < KWIN - RPG; ++i) { ringA[i]=ringA[i+RPG]; ringB[i]=ringB[i+RPG]; }
#pragma unroll
        for (int r = 0; r < RPG; ++r) { ringA[KWIN-RPG+r]=sA[r]; ringB[KWIN-RPG+r]=sB[r]; }
        cur ^= 1;
    }

    // block reduction: 2 waves of 64
#pragma unroll
    for (int off = 32; off > 0; off >>= 1)
        partial += __shfl_down(partial, off);
    if ((t & 63) == 0) red[t >> 6] = partial;
    __syncthreads();
    if (t == 0) atomicAdd(loss_out, (red[0] + red[1]) * INV_NUMEL);
}

extern "C" void kernel_launch(void* const* d_in, const int* in_sizes, int n_in,
                              void* d_out, int out_size, void* d_ws, size_t ws_size,
                              hipStream_t stream) {
    const float* outp = (const float*)d_in[0];
    const float* inp  = (const float*)d_in[1];

    float* ws = (float*)d_ws;
    float* PI = ws;
    float* PP = ws + (size_t)NPLANE;
    float* PS = ws + (size_t)2 * NPLANE;
    float* PA = ws + (size_t)3 * NPLANE;
    float* PB = ws + (size_t)4 * NPLANE;

    hipMemsetAsync(d_out, 0, sizeof(float), stream);

    prep_kernel<<<NPLANE / (256 * 4), 256, 0, stream>>>(outp, inp, PI, PP, PS);

    dim3 grid(WNUM / STRIP, HNUM / SEG, BNUM);   // 4 x 32 x 16 = 2048 blocks
    boxc_ab<<<grid, STRIP, 0, stream>>>(PI, PP, PA, PB);
    boxc_mask_loss<<<grid, STRIP, 0, stream>>>(PA, PB, PI, PS, (float*)d_out);
}

// Round 10
// 203.964 us; speedup vs baseline: 2.4573x; 1.1109x over previous
//
#include <hip/hip_runtime.h>
#include <math.h>

#define BNUM 16
#define HNUM 512
#define WNUM 512
#define HW (HNUM*WNUM)            // 262144
#define NPLANE (BNUM*HW)          // 4194304
#define RR 8
#define KWIN 17
#define EPSF 1e-5f
#define THRESHF 0.8f
#define STRIP 128
#define SEG_AB 32
#define SEG_ML 16
#define RPG 2                      // rows per group
#define RAMPG ((2*RR)/RPG)         // 8 ramp groups before emitting
#define INV_KK (1.0f/289.0f)
#define INV_NUMEL (1.0f/12582912.0f)

// ---------------- Kernel 1: per-pixel prep ----------------
__global__ __launch_bounds__(256) void prep_kernel(
        const float* __restrict__ outp, const float* __restrict__ inp,
        float* __restrict__ PI, float* __restrict__ PP, float* __restrict__ PS) {
    int pix = (blockIdx.x * 256 + threadIdx.x) * 4;
    if (pix >= NPLANE) return;
    int b = pix >> 18;
    int r = pix & (HW - 1);
    size_t base = (size_t)b * 3 * HW + r;

    float4 a0 = *(const float4*)(inp + base);
    float4 a1 = *(const float4*)(inp + base + HW);
    float4 a2 = *(const float4*)(inp + base + 2 * HW);
    float4 b0 = *(const float4*)(outp + base);
    float4 b1 = *(const float4*)(outp + base + HW);
    float4 b2 = *(const float4*)(outp + base + 2 * HW);

    float4 I4, P4, S4;
#define DOCOMP(M) { \
    float i0 = (a0.M + 1.f) * 0.5f; \
    float i1 = (a1.M + 1.f) * 0.5f; \
    float i2 = (a2.M + 1.f) * 0.5f; \
    I4.M = (i0 + i1 + i2) * (1.f/3.f); \
    float mx = fmaxf(i0, fmaxf(i1, i2)); \
    P4.M = (mx > THRESHF) ? 1.f : 0.f; \
    S4.M = 0.5f * (fabsf(b0.M - a0.M) + fabsf(b1.M - a1.M) + fabsf(b2.M - a2.M)); \
}
    DOCOMP(x) DOCOMP(y) DOCOMP(z) DOCOMP(w)
#undef DOCOMP

    size_t po = (size_t)b * HW + r;
    *(float4*)(PI + po) = I4;
    *(float4*)(PP + po) = P4;
    *(float4*)(PS + po) = S4;
}

// ---------------- Kernel 2: box(I,p,I*p,I*I) -> a,b ----------------
// LDS rings (17-deep history is per-thread-column, ~272B/thread -> must be LDS,
// not registers: R9's register rings hit 220 VGPR / 9% occupancy).
// RPG=2 rows per group: 2 loads in flight, half the groups of R7.
// Single-buffered row stage, 2 barriers/group. LDS 39.4KB -> 4 blocks/CU.
__global__ __launch_bounds__(STRIP) void boxc_ab(
        const float* __restrict__ PI, const float* __restrict__ PP,
        float* __restrict__ PA, float* __restrict__ PB) {
    __shared__ float rowI[RPG][STRIP + 2 * RR];
    __shared__ float rowP[RPG][STRIP + 2 * RR];
    __shared__ float ring[4][KWIN][STRIP];

    int t  = threadIdx.x;
    int x0 = blockIdx.x * STRIP;
    int ys = blockIdx.y * SEG_AB;
    int b  = blockIdx.z;

    const float* Ib = PI + (size_t)b * HW;
    const float* Pb = PP + (size_t)b * HW;
    float* Ab = PA + (size_t)b * HW;
    float* Bb = PB + (size_t)b * HW;

    // zero rings: each thread zeroes only its own column slots (i % STRIP == t)
    for (int i = t; i < 4 * KWIN * STRIP; i += STRIP) (&ring[0][0][0])[i] = 0.f;

    int xg  = x0 - RR + t;
    bool xok  = (xg >= 0) && (xg < WNUM);
    int xg2 = x0 - RR + STRIP + t;
    bool x2ok = (t < 2 * RR) && (xg2 < WNUM);

    float vI = 0.f, vP = 0.f, vIp = 0.f, vII = 0.f;
    int slot = 0;

    const int NG = (SEG_AB + 2 * RR) / RPG;   // 24 groups

    // prefetch group 0 (2 rows)
    float pi0[RPG], pp0[RPG], pi1[RPG], pp1[RPG];
#pragma unroll
    for (int r = 0; r < RPG; ++r) {
        pi0[r]=0.f; pp0[r]=0.f; pi1[r]=0.f; pp1[r]=0.f;
        int y = ys - RR + r;
        if (y >= 0 && y < HNUM) {
            size_t ro = (size_t)y * WNUM;
            if (xok)  { pi0[r] = Ib[ro + xg];  pp0[r] = Pb[ro + xg]; }
            if (x2ok) { pi1[r] = Ib[ro + xg2]; pp1[r] = Pb[ro + xg2]; }
        }
    }

    for (int g = 0; g < NG; ++g) {
        // publish current group's rows (regs -> LDS)
#pragma unroll
        for (int r = 0; r < RPG; ++r) { rowI[r][t] = pi0[r]; rowP[r][t] = pp0[r]; }
        if (t < 2 * RR) {
#pragma unroll
            for (int r = 0; r < RPG; ++r) { rowI[r][STRIP+t] = pi1[r]; rowP[r][STRIP+t] = pp1[r]; }
        }
        // issue next group's loads (2 independent rows -> regs; regs are the dbuf)
#pragma unroll
        for (int r = 0; r < RPG; ++r) { pi0[r]=0.f; pp0[r]=0.f; pi1[r]=0.f; pp1[r]=0.f; }
        if (g + 1 < NG) {
#pragma unroll
            for (int r = 0; r < RPG; ++r) {
                int y = ys - RR + (g + 1) * RPG + r;
                if (y >= 0 && y < HNUM) {
                    size_t ro = (size_t)y * WNUM;
                    if (xok)  { pi0[r] = Ib[ro + xg];  pp0[r] = Pb[ro + xg]; }
                    if (x2ok) { pi1[r] = Ib[ro + xg2]; pp1[r] = Pb[ro + xg2]; }
                }
            }
        }
        __syncthreads();   // rows visible

        bool emit = (g >= RAMPG);   // uniform
#pragma unroll
        for (int r = 0; r < RPG; ++r) {
            float sI=0.f, sP=0.f, sIp=0.f, sII=0.f;
#pragma unroll
            for (int d = 0; d < KWIN; ++d) {
                float iv = rowI[r][t + d];
                float pv = rowP[r][t + d];
                sI += iv; sP += pv; sIp += iv * pv; sII += iv * iv;
            }
            vI  += sI  - ring[0][slot][t]; ring[0][slot][t] = sI;
            vP  += sP  - ring[1][slot][t]; ring[1][slot][t] = sP;
            vIp += sIp - ring[2][slot][t]; ring[2][slot][t] = sIp;
            vII += sII - ring[3][slot][t]; ring[3][slot][t] = sII;
            slot = (slot + 1 == KWIN) ? 0 : slot + 1;

            if (emit) {
                int k = g * RPG + r;
                int yout = ys + k - 2 * RR;
                float mI  = vI  * INV_KK;
                float mP  = vP  * INV_KK;
                float mIp = vIp * INV_KK;
                float mII = vII * INV_KK;
                float cov = mIp - mI * mP;
                float var = mII - mI * mI;
                float a   = cov / (var + EPSF);
                float bb  = mP - a * mI;
                size_t off = (size_t)yout * WNUM + x0 + t;
                Ab[off] = a;
                Bb[off] = bb;
            }
        }
        __syncthreads();   // all reads done before next publish overwrites rows
    }
}

// ---------------- Kernel 3: box(a), box(b) -> mask -> loss ----------------
// LDS 22.0KB -> 7 blocks/CU (14 waves).
__global__ __launch_bounds__(STRIP) void boxc_mask_loss(
        const float* __restrict__ PA, const float* __restrict__ PB,
        const float* __restrict__ PI, const float* __restrict__ PS,
        float* __restrict__ loss_out) {
    __shared__ float rowA[RPG][STRIP + 2 * RR];
    __shared__ float rowB[RPG][STRIP + 2 * RR];
    __shared__ float ring[2][KWIN][STRIP];
    __shared__ float red[2];

    int t  = threadIdx.x;
    int x0 = blockIdx.x * STRIP;
    int ys = blockIdx.y * SEG_ML;
    int b  = blockIdx.z;

    const float* Ab = PA + (size_t)b * HW;
    const float* Bb = PB + (size_t)b * HW;
    const float* Ib = PI + (size_t)b * HW;
    const float* Sb = PS + (size_t)b * HW;

    for (int i = t; i < 2 * KWIN * STRIP; i += STRIP) (&ring[0][0][0])[i] = 0.f;

    int xg  = x0 - RR + t;
    bool xok  = (xg >= 0) && (xg < WNUM);
    int xg2 = x0 - RR + STRIP + t;
    bool x2ok = (t < 2 * RR) && (xg2 < WNUM);

    float vA = 0.f, vB = 0.f;
    int slot = 0;
    float partial = 0.f;

    const int NG = (SEG_ML + 2 * RR) / RPG;   // 16 groups

    float pa0[RPG], pb0[RPG], pa1[RPG], pb1[RPG];
#pragma unroll
    for (int r = 0; r < RPG; ++r) {
        pa0[r]=0.f; pb0[r]=0.f; pa1[r]=0.f; pb1[r]=0.f;
        int y = ys - RR + r;
        if (y >= 0 && y < HNUM) {
            size_t ro = (size_t)y * WNUM;
            if (xok)  { pa0[r] = Ab[ro + xg];  pb0[r] = Bb[ro + xg]; }
            if (x2ok) { pa1[r] = Ab[ro + xg2]; pb1[r] = Bb[ro + xg2]; }
        }
    }

    for (int g = 0; g < NG; ++g) {
#pragma unroll
        for (int r = 0; r < RPG; ++r) { rowA[r][t] = pa0[r]; rowB[r][t] = pb0[r]; }
        if (t < 2 * RR) {
#pragma unroll
            for (int r = 0; r < RPG; ++r) { rowA[r][STRIP+t] = pa1[r]; rowB[r][STRIP+t] = pb1[r]; }
        }
#pragma unroll
        for (int r = 0; r < RPG; ++r) { pa0[r]=0.f; pb0[r]=0.f; pa1[r]=0.f; pb1[r]=0.f; }
        if (g + 1 < NG) {
#pragma unroll
            for (int r = 0; r < RPG; ++r) {
                int y = ys - RR + (g + 1) * RPG + r;
                if (y >= 0 && y < HNUM) {
                    size_t ro = (size_t)y * WNUM;
                    if (xok)  { pa0[r] = Ab[ro + xg];  pb0[r] = Bb[ro + xg]; }
                    if (x2ok) { pa1[r] = Ab[ro + xg2]; pb1[r] = Bb[ro + xg2]; }
                }
            }
        }
        __syncthreads();

        bool emit = (g >= RAMPG);
#pragma unroll
        for (int r = 0; r < RPG; ++r) {
            float sA=0.f, sB=0.f;
#pragma unroll
            for (int d = 0; d < KWIN; ++d) {
                sA += rowA[r][t + d];
                sB += rowB[r][t + d];
            }
            vA += sA - ring[0][slot][t]; ring[0][slot][t] = sA;
            vB += sB - ring[1][slot][t]; ring[1][slot][t] = sB;
            slot = (slot + 1 == KWIN) ? 0 : slot + 1;

            if (emit) {
                int k = g * RPG + r;
                int yout = ys + k - 2 * RR;
                float mA = vA * INV_KK;
                float mB = vB * INV_KK;
                size_t off = (size_t)yout * WNUM + x0 + t;
                float refined = mA * Ib[off] + mB;
                float mask = fminf(fmaxf(refined, 0.f), 1.f);
                partial += mask * Sb[off];
            }
        }
        __syncthreads();
    }

    // block reduction: 2 waves of 64
#pragma unroll
    for (int off = 32; off > 0; off >>= 1)
        partial += __shfl_down(partial, off);
    if ((t & 63) == 0) red[t >> 6] = partial;
    __syncthreads();
    if (t == 0) atomicAdd(loss_out, (red[0] + red[1]) * INV_NUMEL);
}

extern "C" void kernel_launch(void* const* d_in, const int* in_sizes, int n_in,
                              void* d_out, int out_size, void* d_ws, size_t ws_size,
                              hipStream_t stream) {
    const float* outp = (const float*)d_in[0];
    const float* inp  = (const float*)d_in[1];

    float* ws = (float*)d_ws;
    float* PI = ws;
    float* PP = ws + (size_t)NPLANE;
    float* PS = ws + (size_t)2 * NPLANE;
    float* PA = ws + (size_t)3 * NPLANE;
    float* PB = ws + (size_t)4 * NPLANE;

    hipMemsetAsync(d_out, 0, sizeof(float), stream);

    prep_kernel<<<NPLANE / (256 * 4), 256, 0, stream>>>(outp, inp, PI, PP, PS);

    dim3 grid_ab(WNUM / STRIP, HNUM / SEG_AB, BNUM);   // 4 x 16 x 16 = 1024
    boxc_ab<<<grid_ab, STRIP, 0, stream>>>(PI, PP, PA, PB);

    dim3 grid_ml(WNUM / STRIP, HNUM / SEG_ML, BNUM);   // 4 x 32 x 16 = 2048
    boxc_mask_loss<<<grid_ml, STRIP, 0, stream>>>(PA, PB, PI, PS, (float*)d_out);
}